// Round 16
// baseline (104.325 us; speedup 1.0000x reference)
//
#include <hip/hip_runtime.h>
#include <cstdint>

// Problem constants
#define N_TOK 4096   // B*T
#define D_    1024
#define E_    8
#define I_    512
#define PAD   64     // expert segments padded to 64
#define CAP   (N_TOK*2 + E_*PAD)     // 8704 max padded positions
#define NBT   1088                   // tile blocks per GEMM (136 x-tiles x 8 panels)
#define WSZ   ((size_t)E_ * I_ * D_) // one weight's element count

typedef __attribute__((ext_vector_type(16))) float f32x16;
typedef __attribute__((ext_vector_type(8)))  short bf16x8;

__device__ inline unsigned short f2bf(float f) {
  union { float f; uint32_t u; } v; v.f = f;
  uint32_t r = v.u + 0x7fffu + ((v.u >> 16) & 1u);
  return (unsigned short)(r >> 16);
}
__device__ inline float bf2f(unsigned short h) {
  union { uint32_t u; float f; } v; v.u = ((uint32_t)h) << 16;
  return v.f;
}

#define GLOAD_LDS16(gp, lp)                                                        \
  __builtin_amdgcn_global_load_lds((const __attribute__((address_space(1))) void*)(gp), \
                                   (__attribute__((address_space(3))) void*)(lp), 16, 0, 0)

// per-wave load fence: waits THIS wave's gload_lds only (vmcnt is per-wave HW state).
#define WAVE_FENCE                                       \
  do {                                                   \
    asm volatile("s_waitcnt vmcnt(0)" ::: "memory");     \
    __builtin_amdgcn_sched_barrier(0);                   \
  } while (0)

// ---------------- prep: Wg/Wu converts (blocks 0..8191) ∥ router (8192..9215) ----------------
__global__ __launch_bounds__(256) void prep_kernel(const float* __restrict__ x,
                                                   const float* __restrict__ rw,
                                                   const float* __restrict__ wg,
                                                   const float* __restrict__ wu,
                                                   float* __restrict__ logits,
                                                   int* __restrict__ sel,
                                                   float* __restrict__ prob,
                                                   unsigned short* __restrict__ Xb,
                                                   unsigned short* __restrict__ Wb) {
  int b = blockIdx.x;
  if (b < 2 * 4096) {
    const int y = b >> 12;
    const float* s = (y == 0) ? wg : wu;
    unsigned short* d = Wb + (size_t)y * WSZ;
    const int i = (b & 4095) * 256 + threadIdx.x;
    const float4 v = reinterpret_cast<const float4*>(s)[i];
    ushort4 o;
    o.x = f2bf(v.x); o.y = f2bf(v.y); o.z = f2bf(v.z); o.w = f2bf(v.w);
    reinterpret_cast<ushort4*>(d)[i] = o;
    return;
  }
  b -= 2 * 4096;   // router: 1024 blocks, 4 tokens each
  const int lane = threadIdx.x & 63;
  const int tok  = b * 4 + (threadIdx.x >> 6);
  const float4* xr = reinterpret_cast<const float4*>(x + (size_t)tok * D_);
  float4 xv[4];
#pragma unroll
  for (int q = 0; q < 4; ++q) xv[q] = xr[q * 64 + lane];
  float acc[E_];
#pragma unroll
  for (int e = 0; e < E_; ++e) {
    const float4* wr = reinterpret_cast<const float4*>(rw + (size_t)e * D_);
    float s = 0.f;
#pragma unroll
    for (int q = 0; q < 4; ++q) {
      float4 wv = wr[q * 64 + lane];
      s += xv[q].x * wv.x + xv[q].y * wv.y + xv[q].z * wv.z + xv[q].w * wv.w;
    }
    acc[e] = s;
  }
  ushort4* xb = reinterpret_cast<ushort4*>(Xb + (size_t)tok * D_);
#pragma unroll
  for (int q = 0; q < 4; ++q) {
    ushort4 o;
    o.x = f2bf(xv[q].x); o.y = f2bf(xv[q].y); o.z = f2bf(xv[q].z); o.w = f2bf(xv[q].w);
    xb[q * 64 + lane] = o;
  }
#pragma unroll
  for (int e = 0; e < E_; ++e)
#pragma unroll
    for (int off = 32; off; off >>= 1) acc[e] += __shfl_xor(acc[e], off);
  if (lane == 0) {
    float v0 = -1e30f, v1 = -1e30f; int i0 = 0, i1 = 0;
#pragma unroll
    for (int e = 0; e < E_; ++e) {
      float v = acc[e];
      logits[(size_t)tok * E_ + e] = v;
      if (v > v0)      { v1 = v0; i1 = i0; v0 = v; i0 = e; }
      else if (v > v1) { v1 = v;  i1 = e; }
    }
    float t  = __expf(v1 - v0);
    sel[tok * 2] = i0; sel[tok * 2 + 1] = i1;
    prob[tok * 2] = 1.f / (1.f + t);
    prob[tok * 2 + 1] = t / (1.f + t);
  }
}

// ---------------- plan: counts (ballot), padded offsets, scatter, pads ----------------
__global__ __launch_bounds__(1024) void plan_kernel(const int* __restrict__ sel,
                                                    const float* __restrict__ prob,
                                                    int* __restrict__ offs,
                                                    int* __restrict__ ptok,
                                                    float* __restrict__ pprob,
                                                    int* __restrict__ tpos) {
  __shared__ int wcnt[16][E_];
  __shared__ int pfx[16][E_];
  __shared__ int soffs[E_ + 1];
  __shared__ int secnt[E_];
  const int tid = threadIdx.x;
  const int wave = tid >> 6, lane = tid & 63;
  const unsigned long long lt = (1ull << lane) - 1ull;

  int   mye[8];
  int   mylp[8];
  float myp[8];
  int run[E_];
#pragma unroll
  for (int e = 0; e < E_; ++e) run[e] = 0;

#pragma unroll
  for (int it = 0; it < 8; ++it) {
    int i = wave * 512 + it * 64 + lane;
    int e = sel[i];
    mye[it] = e;
    myp[it] = prob[i];
    int lp = 0;
#pragma unroll
    for (int ee = 0; ee < E_; ++ee) {
      unsigned long long m = __ballot(e == ee);
      if (e == ee) lp = run[ee] + __popcll(m & lt);
      run[ee] += __popcll(m);
    }
    mylp[it] = lp;
  }
#pragma unroll
  for (int ee = 0; ee < E_; ++ee)
    if (lane == ee) wcnt[wave][ee] = run[ee];
  __syncthreads();

  if (tid == 0) {
    int ro = 0;
#pragma unroll
    for (int e = 0; e < E_; ++e) {
      int c = 0;
      int r = ro;
      for (int w = 0; w < 16; ++w) { pfx[w][e] = r; r += wcnt[w][e]; c += wcnt[w][e]; }
      soffs[e] = ro; offs[e] = ro; secnt[e] = c;
      ro += (c + PAD - 1) & ~(PAD - 1);
    }
    soffs[E_] = ro; offs[E_] = ro;
  }
  __syncthreads();

#pragma unroll
  for (int it = 0; it < 8; ++it) {
    int i = wave * 512 + it * 64 + lane;
    int pos = pfx[wave][mye[it]] + mylp[it];
    ptok[pos]  = i >> 1;
    pprob[pos] = myp[it];
    tpos[i]    = pos;
  }
  // padding: token 0 (valid gather target), prob 0; pad rows never combined
#pragma unroll
  for (int e = 0; e < E_; ++e) {
    int s = soffs[e] + secnt[e];
    int npad = soffs[e + 1] - s;
    if (tid < npad) { ptok[s + tid] = 0; pprob[s + tid] = 0.f; }
  }
}

// ---------------- GEMM1: H = silu(X Wg^T) * (X Wu^T) — wave-independent ----------------
// Block = 4 independent waves, each owning a 32pos x 32I tile + private 12KB LDS.
// NO __syncthreads in the K-loop: per-wave gload_lds + vmcnt(0); 12 free-running
// wave-streams/CU hide staging latency. Blocks >= NBT stream the Wd fp32->bf16
// convert on gemm1's idle HBM bandwidth.
__global__ __launch_bounds__(256, 3) void gemm1_kernel(const unsigned short* __restrict__ Xb,
                                                       const unsigned short* __restrict__ Wg,
                                                       const unsigned short* __restrict__ Wu,
                                                       const float* __restrict__ wd,
                                                       const int* __restrict__ ptok,
                                                       const int* __restrict__ offs,
                                                       unsigned short* __restrict__ Wdb,
                                                       unsigned short* __restrict__ H) {
  __shared__ unsigned short lds[4][3][2048];   // [wave][A|Bg|Bu][32 rows x 64] = 48KB
  const int bid = blockIdx.x;
  const int tid = threadIdx.x;
  const int lane = tid & 63;
  const int w    = tid >> 6;

  if (bid >= NBT) {   // ---- Wd convert blocks (dispatched after tile blocks) ----
    const int base = (bid - NBT) * 256 + tid;
#pragma unroll
    for (int it = 0; it < 4; ++it) {
      const int idx = base + it * 1024 * 256;   // WSZ/4 = 1048576
      const float4 v = reinterpret_cast<const float4*>(wd)[idx];
      ushort4 o;
      o.x = f2bf(v.x); o.y = f2bf(v.y); o.z = f2bf(v.z); o.w = f2bf(v.w);
      reinterpret_cast<ushort4*>(Wdb)[idx] = o;
    }
    return;
  }

  const int wgid = (bid & 7) * 136 + (bid >> 3);   // bijective XCD-chunked
  const int bx = wgid >> 3;          // 0..135 : position tile (64 rows)
  const int by = wgid & 7;           // 0..7   : I-panel (64 cols)
  const int total = offs[E_];
  const int t0 = bx * 64;
  if (t0 >= total) return;
  int e = 0;
#pragma unroll
  for (int i = 1; i < E_; ++i) if (offs[i] <= t0) e = i;

  const int wr = w >> 1, wc = w & 1;
  const int wt0 = t0 + wr * 32;          // wave's position base
  const int ic0 = by * 64 + wc * 32;     // wave's I base
  const int gc8 = ((lane & 7) ^ (lane >> 3)) * 8;   // pre-swizzled src col (ushorts)

  // per-lane token gather (no shared toks array -> no barrier)
  const unsigned short* asrc[4];
  const unsigned short* bgsrc[4];
  const unsigned short* busrc[4];
#pragma unroll
  for (int j = 0; j < 4; ++j) {
    const int r = j * 8 + (lane >> 3);                 // 0..31 within wave tile
    asrc[j] = Xb + (size_t)ptok[wt0 + r] * D_ + gc8;
    const size_t ro = ((size_t)e * I_ + ic0 + r) * D_ + gc8;
    bgsrc[j] = Wg + ro;
    busrc[j] = Wu + ro;
  }

  unsigned short* A  = lds[w][0];
  unsigned short* Bg = lds[w][1];
  unsigned short* Bu = lds[w][2];

  f32x16 accg, accu;
#pragma unroll
  for (int j = 0; j < 16; ++j) { accg[j] = 0.f; accu[j] = 0.f; }

  const int arow64 = (lane & 31) * 64;   // wave-private row offset (ushorts)

  for (int k0 = 0; k0 < D_; k0 += 64) {
#pragma unroll
    for (int j = 0; j < 4; ++j) {
      GLOAD_LDS16(asrc[j] + k0, &A[j * 512]);
      GLOAD_LDS16(bgsrc[j] + k0, &Bg[j * 512]);
      GLOAD_LDS16(busrc[j] + k0, &Bu[j * 512]);
    }
    WAVE_FENCE;   // own 12 loads retired; no block barrier
#pragma unroll
    for (int sk = 0; sk < 4; ++sk) {
      const int uoff = ((sk * 2 + (lane >> 5)) ^ (lane & 7)) * 8;
      bf16x8 a  = *reinterpret_cast<const bf16x8*>(&A[arow64 + uoff]);
      bf16x8 bg = *reinterpret_cast<const bf16x8*>(&Bg[arow64 + uoff]);
      bf16x8 bu = *reinterpret_cast<const bf16x8*>(&Bu[arow64 + uoff]);
      accg = __builtin_amdgcn_mfma_f32_32x32x16_bf16(bg, a, accg, 0, 0, 0);
      accu = __builtin_amdgcn_mfma_f32_32x32x16_bf16(bu, a, accu, 0, 0, 0);
    }
    __builtin_amdgcn_sched_barrier(0);   // keep next-step gloads below this compute
  }

  // swapped-operand 32x32 C/D: position = lane&31, I-idx = (reg&3)+8*(reg>>2)+4*(lane>>5)
  const int hrow = wt0 + (lane & 31);
#pragma unroll
  for (int q = 0; q < 4; ++q) {
    const int icb = ic0 + q * 8 + (lane >> 5) * 4;
    ushort4 st;
    float g, uu, h;
    g = accg[q*4+0]; uu = accu[q*4+0]; h = (g / (1.f + __expf(-g))) * uu; st.x = f2bf(h);
    g = accg[q*4+1]; uu = accu[q*4+1]; h = (g / (1.f + __expf(-g))) * uu; st.y = f2bf(h);
    g = accg[q*4+2]; uu = accu[q*4+2]; h = (g / (1.f + __expf(-g))) * uu; st.z = f2bf(h);
    g = accg[q*4+3]; uu = accu[q*4+3]; h = (g / (1.f + __expf(-g))) * uu; st.w = f2bf(h);
    *reinterpret_cast<ushort4*>(&H[(size_t)hrow * I_ + icb]) = st;
  }
}

// ---------------- GEMM2: Opos[pos] = prob * (H Wd^T) — wave-independent ----------------
// Block = 4 waves, each 32pos x 64D tile, private 12KB LDS (A 32x64 | B 64x64),
// no K-loop barriers. (R15 bug: this array was declared 24KB but indexed as 48KB.)
__global__ __launch_bounds__(256, 3) void gemm2_kernel(const unsigned short* __restrict__ H,
                                                       const unsigned short* __restrict__ Wd,
                                                       const float* __restrict__ pprob,
                                                       const int* __restrict__ offs,
                                                       unsigned short* __restrict__ O) {
  __shared__ unsigned short lds[4][6144];   // [wave][A 2048 | B 4096] ushorts = 48KB
  const int bid = blockIdx.x;
  const int tid = threadIdx.x;
  const int lane = tid & 63;
  const int w    = tid >> 6;

  const int wgid = (bid & 7) * 136 + (bid >> 3);
  const int bx = wgid >> 3;          // 0..135 : position tile
  const int by = wgid & 7;           // 0..7   : D-panel (128 cols)
  const int total = offs[E_];
  const int t0 = bx * 64;
  if (t0 >= total) return;
  int e = 0;
#pragma unroll
  for (int i = 1; i < E_; ++i) if (offs[i] <= t0) e = i;

  const int wr = w >> 1, wc = w & 1;
  const int wt0 = t0 + wr * 32;            // wave's position base
  const int dc0 = by * 128 + wc * 64;      // wave's D base (64 cols)
  const int gc8 = ((lane & 7) ^ (lane >> 3)) * 8;

  unsigned short* A = &lds[w][0];          // 32x64
  unsigned short* B = A + 2048;            // 64x64

  const unsigned short* asrc[4];
#pragma unroll
  for (int j = 0; j < 4; ++j) {
    const int r = j * 8 + (lane >> 3);
    asrc[j] = H + (size_t)(wt0 + r) * I_ + gc8;
  }
  const unsigned short* bsrc[8];
#pragma unroll
  for (int j = 0; j < 8; ++j) {
    const int r = j * 8 + (lane >> 3);                 // 0..63
    bsrc[j] = Wd + ((size_t)e * D_ + dc0 + r) * I_ + gc8;
  }

  f32x16 acc0, acc1;
#pragma unroll
  for (int j = 0; j < 16; ++j) { acc0[j] = 0.f; acc1[j] = 0.f; }

  const int arow64 = (lane & 31) * 64;

  for (int k0 = 0; k0 < I_; k0 += 64) {
#pragma unroll
    for (int j = 0; j < 4; ++j) GLOAD_LDS16(asrc[j] + k0, &A[j * 512]);
#pragma unroll
    for (int j = 0; j < 8; ++j) GLOAD_LDS16(bsrc[j] + k0, &B[j * 512]);
    WAVE_FENCE;
#pragma unroll
    for (int sk = 0; sk < 4; ++sk) {
      const int uoff = ((sk * 2 + (lane >> 5)) ^ (lane & 7)) * 8;
      bf16x8 a  = *reinterpret_cast<const bf16x8*>(&A[arow64 + uoff]);
      bf16x8 b0 = *reinterpret_cast<const bf16x8*>(&B[arow64 + uoff]);
      bf16x8 b1 = *reinterpret_cast<const bf16x8*>(&B[2048 + arow64 + uoff]);
      acc0 = __builtin_amdgcn_mfma_f32_32x32x16_bf16(b0, a, acc0, 0, 0, 0);
      acc1 = __builtin_amdgcn_mfma_f32_32x32x16_bf16(b1, a, acc1, 0, 0, 0);
    }
    __builtin_amdgcn_sched_barrier(0);
  }

  const float p = pprob[wt0 + (lane & 31)];
  const int orow = wt0 + (lane & 31);
#pragma unroll
  for (int q = 0; q < 4; ++q) {
    const int dcb = dc0 + q * 8 + (lane >> 5) * 4;
    ushort4 v;
    v.x = f2bf(acc0[q*4+0] * p); v.y = f2bf(acc0[q*4+1] * p);
    v.z = f2bf(acc0[q*4+2] * p); v.w = f2bf(acc0[q*4+3] * p);
    *reinterpret_cast<ushort4*>(&O[(size_t)orow * D_ + dcb]) = v;
    ushort4 v1;
    v1.x = f2bf(acc1[q*4+0] * p); v1.y = f2bf(acc1[q*4+1] * p);
    v1.z = f2bf(acc1[q*4+2] * p); v1.w = f2bf(acc1[q*4+3] * p);
    *reinterpret_cast<ushort4*>(&O[(size_t)orow * D_ + dcb + 32]) = v1;
  }
}

// ---------------- combine: out[t] = O[pos0] + O[pos1] (bf16 in, fp32 out) ----------------
__global__ __launch_bounds__(256) void combine_kernel(const unsigned short* __restrict__ O,
                                                      const int* __restrict__ tpos,
                                                      float* __restrict__ out) {
  const int t = blockIdx.x;
  const int c = threadIdx.x;
  const int p0 = tpos[2 * t], p1 = tpos[2 * t + 1];
  const ushort4 a = reinterpret_cast<const ushort4*>(O + (size_t)p0 * D_)[c];
  const ushort4 b = reinterpret_cast<const ushort4*>(O + (size_t)p1 * D_)[c];
  float4 r;
  r.x = bf2f(a.x) + bf2f(b.x); r.y = bf2f(a.y) + bf2f(b.y);
  r.z = bf2f(a.z) + bf2f(b.z); r.w = bf2f(a.w) + bf2f(b.w);
  reinterpret_cast<float4*>(out + (size_t)t * D_)[c] = r;
}

extern "C" void kernel_launch(void* const* d_in, const int* in_sizes, int n_in,
                              void* d_out, int out_size, void* d_ws, size_t ws_size,
                              hipStream_t stream) {
  const float* x  = (const float*)d_in[0];
  const float* rw = (const float*)d_in[1];
  const float* wg = (const float*)d_in[2];
  const float* wu = (const float*)d_in[3];
  const float* wd = (const float*)d_in[4];
  float* out    = (float*)d_out;
  float* logits = out + (size_t)N_TOK * D_;   // second output region

  char* ws = (char*)d_ws;
  int*   offs  = (int*)  (ws + 64);
  int*   sel   = (int*)  (ws + 4352);
  float* prob  = (float*)(ws + 37120);
  int*   ptok  = (int*)  (ws + 69888);    // CAP ints
  float* pprob = (float*)(ws + 104704);   // CAP floats
  int*   tpos  = (int*)  (ws + 139520);   // 8192 ints
  unsigned short* Xb  = (unsigned short*)(ws + 172288);
  unsigned short* Wgb = Xb  + (size_t)N_TOK * D_;
  unsigned short* Wub = Wgb + WSZ;
  unsigned short* Wdb = Wub + WSZ;
  unsigned short* Hb  = Wdb + WSZ;                          // [CAP, I_] bf16
  unsigned short* Opos = Hb + (size_t)CAP * I_;             // [CAP, D_] bf16

  prep_kernel<<<2 * 4096 + N_TOK / 4, 256, 0, stream>>>(x, rw, wg, wu,
                                                        logits, sel, prob, Xb, Wgb);
  plan_kernel<<<1, 1024, 0, stream>>>(sel, prob, offs, ptok, pprob, tpos);
  gemm1_kernel<<<NBT + 1024, 256, 0, stream>>>(Xb, Wgb, Wub, wd, ptok, offs, Wdb, Hb);
  gemm2_kernel<<<NBT, 256, 0, stream>>>(Hb, Wdb, pprob, offs, Opos);
  combine_kernel<<<N_TOK, 256, 0, stream>>>(Opos, tpos, out);
}